// Round 1
// baseline (791.521 us; speedup 1.0000x reference)
//
#include <hip/hip_runtime.h>
#include <hip/hip_bf16.h>

typedef unsigned short ushort_t;
typedef unsigned int uint32;

typedef __attribute__((ext_vector_type(8))) short bf16x8;
typedef __attribute__((ext_vector_type(4))) float f32x4;

__device__ __forceinline__ ushort_t f2bf(float f) {
    uint32 u = __float_as_uint(f);
    u += 0x7FFFu + ((u >> 16) & 1u);   // round-to-nearest-even
    return (ushort_t)(u >> 16);
}
__device__ __forceinline__ float bf2f(ushort_t b) {
    return __uint_as_float(((uint32)b) << 16);
}

// ---------------------------------------------------------------------------
// K0: Mcomb[h*256+d][e] = sum_a W_k[h][a][d] * W_q[h][a][e] / 8   (bf16)
//     WoutB = bf16(W_out)   (both 131072 elements)
// ---------------------------------------------------------------------------
__global__ __launch_bounds__(256) void prep_kernel(
        const float* __restrict__ Wq, const float* __restrict__ Wk,
        const float* __restrict__ Wout,
        ushort_t* __restrict__ Mcomb, ushort_t* __restrict__ WoutB) {
    int idx = blockIdx.x * 256 + threadIdx.x;   // 0..131071
    int n = idx >> 8;        // 0..511
    int e = idx & 255;
    int h = n >> 8;
    int d = n & 255;
    const float* wk = Wk + (h << 14);
    const float* wq = Wq + (h << 14);
    float acc = 0.f;
#pragma unroll 8
    for (int a = 0; a < 64; ++a) {
        acc += wk[(a << 8) + d] * wq[(a << 8) + e];
    }
    Mcomb[idx] = f2bf(acc * 0.125f);
    WoutB[idx] = f2bf(Wout[idx]);
}

// ---------------------------------------------------------------------------
// K1: qk[b][n] = sum_e center[b][e] * Mcomb[n][e]    (bf16 out)
// C = A(32768x256 fp32->bf16) * W^T, W = Mcomb (512x256 bf16)
// tile: BM=64, BN=128, BK=64; 256 thr = 4 waves (2x2), wave = 32x64 (2x4 MFMA)
// ---------------------------------------------------------------------------
#define LDT 72   // padded LDS row stride (ushorts), 144 B

__global__ __launch_bounds__(256) void gemm_qk(
        const float* __restrict__ A, const ushort_t* __restrict__ Bw,
        ushort_t* __restrict__ C) {
    __shared__ ushort_t As[64 * LDT];    // 9216 B
    __shared__ ushort_t Bs[128 * LDT];   // 18432 B
    const int t = threadIdx.x;
    const int m0 = blockIdx.x * 64;
    const int n0 = blockIdx.y * 128;
    const int lane = t & 63;
    const int w = t >> 6;
    const int wm = (w & 1) * 32;
    const int wn = (w >> 1) * 64;

    f32x4 zero = {0.f, 0.f, 0.f, 0.f};
    f32x4 acc[2][4];
#pragma unroll
    for (int i = 0; i < 2; ++i)
#pragma unroll
        for (int j = 0; j < 4; ++j) acc[i][j] = zero;

    for (int kc = 0; kc < 256; kc += 64) {
        __syncthreads();
        // stage A (fp32 -> bf16): 64x64
#pragma unroll
        for (int i = 0; i < 4; ++i) {
            int f = i * 1024 + t * 4;
            int r = f >> 6;
            int c = f & 63;
            float4 v = *reinterpret_cast<const float4*>(&A[(size_t)(m0 + r) * 256 + kc + c]);
            ushort_t p[4] = {f2bf(v.x), f2bf(v.y), f2bf(v.z), f2bf(v.w)};
            *reinterpret_cast<uint2*>(&As[r * LDT + c]) = *reinterpret_cast<uint2*>(p);
        }
        // stage B (bf16): 128x64
#pragma unroll
        for (int i = 0; i < 4; ++i) {
            int f = i * 2048 + t * 8;
            int r = f >> 6;
            int c = f & 63;
            uint4 v = *reinterpret_cast<const uint4*>(&Bw[(size_t)(n0 + r) * 256 + kc + c]);
            *reinterpret_cast<uint4*>(&Bs[r * LDT + c]) = v;
        }
        __syncthreads();
#pragma unroll
        for (int s = 0; s < 2; ++s) {
            int kb = s * 32 + (lane >> 4) * 8;
            bf16x8 af[2], bfr[4];
#pragma unroll
            for (int i = 0; i < 2; ++i)
                af[i] = *reinterpret_cast<const bf16x8*>(&As[(wm + i * 16 + (lane & 15)) * LDT + kb]);
#pragma unroll
            for (int j = 0; j < 4; ++j)
                bfr[j] = *reinterpret_cast<const bf16x8*>(&Bs[(wn + j * 16 + (lane & 15)) * LDT + kb]);
#pragma unroll
            for (int i = 0; i < 2; ++i)
#pragma unroll
                for (int j = 0; j < 4; ++j)
                    acc[i][j] = __builtin_amdgcn_mfma_f32_16x16x32_bf16(af[i], bfr[j], acc[i][j], 0, 0, 0);
        }
    }
    const int cn = lane & 15;
    const int r4 = (lane >> 4) * 4;
#pragma unroll
    for (int i = 0; i < 2; ++i)
#pragma unroll
        for (int j = 0; j < 4; ++j)
#pragma unroll
            for (int r = 0; r < 4; ++r) {
                int m = m0 + wm + i * 16 + r4 + r;
                int n = n0 + wn + j * 16 + cn;
                C[(size_t)m * 512 + n] = f2bf(acc[i][j][r]);
            }
}

// ---------------------------------------------------------------------------
// K2: per row b: scores[h][k] = sum_d qk[b][h*256+d]*x[k][d]  (pre-scaled)
//     softmax over k, * w, renorm(+1e-8); ctx[b][h*256+d] = sum_k attn*x
// 1 wave per row, 4 rows/block. x staged bf16 in LDS, math fp32.
// ---------------------------------------------------------------------------
#define XSS 264   // xs row stride in ushorts (528 B)

__global__ __launch_bounds__(256) void attn_kernel(
        const float* __restrict__ neigh, const float* __restrict__ wts,
        const ushort_t* __restrict__ qk, ushort_t* __restrict__ ctx) {
    __shared__ ushort_t xs[4][16 * XSS];   // 33792 B
    __shared__ float qs[4][512];           // 8192 B
    __shared__ float at[4][32];            // 512 B
    const int t = threadIdx.x;
    const int w = t >> 6;
    const int lane = t & 63;
    const size_t b = (size_t)blockIdx.x * 4 + w;

    // stage x: 16 x 256 fp32 -> bf16
    const float* xg = neigh + b * 4096;
#pragma unroll
    for (int k = 0; k < 16; ++k) {
        float4 v = *reinterpret_cast<const float4*>(&xg[k * 256 + lane * 4]);
        ushort_t p[4] = {f2bf(v.x), f2bf(v.y), f2bf(v.z), f2bf(v.w)};
        *reinterpret_cast<uint2*>(&xs[w][k * XSS + lane * 4]) = *reinterpret_cast<uint2*>(p);
    }
    // stage qk: 512 bf16 -> fp32
    {
        uint4 v = *reinterpret_cast<const uint4*>(&qk[b * 512 + lane * 8]);
        const ushort_t* xu = reinterpret_cast<const ushort_t*>(&v);
        float4 q0 = {bf2f(xu[0]), bf2f(xu[1]), bf2f(xu[2]), bf2f(xu[3])};
        float4 q1 = {bf2f(xu[4]), bf2f(xu[5]), bf2f(xu[6]), bf2f(xu[7])};
        *reinterpret_cast<float4*>(&qs[w][lane * 8]) = q0;
        *reinterpret_cast<float4*>(&qs[w][lane * 8 + 4]) = q1;
    }
    __syncthreads();

    // scores: lane -> (h,k,half); 2 lanes per (h,k) dot of 256
    const int p = lane & 31;
    const int half = lane >> 5;
    const int h = p >> 4;
    const int kn = p & 15;
    const ushort_t* xrow = &xs[w][kn * XSS + half * 128];
    const float* qrow = &qs[w][h * 256 + half * 128];
    float sc = 0.f;
#pragma unroll
    for (int j = 0; j < 16; ++j) {
        uint4 xv = *reinterpret_cast<const uint4*>(xrow + j * 8);
        const ushort_t* xu = reinterpret_cast<const ushort_t*>(&xv);
        float4 q0 = *reinterpret_cast<const float4*>(qrow + j * 8);
        float4 q1 = *reinterpret_cast<const float4*>(qrow + j * 8 + 4);
        sc += bf2f(xu[0]) * q0.x;
        sc += bf2f(xu[1]) * q0.y;
        sc += bf2f(xu[2]) * q0.z;
        sc += bf2f(xu[3]) * q0.w;
        sc += bf2f(xu[4]) * q1.x;
        sc += bf2f(xu[5]) * q1.y;
        sc += bf2f(xu[6]) * q1.z;
        sc += bf2f(xu[7]) * q1.w;
    }
    sc += __shfl_xor(sc, 32);

    // softmax over k (groups of 16 lanes), * w, renorm
    float mx = sc;
#pragma unroll
    for (int m = 1; m < 16; m <<= 1) mx = fmaxf(mx, __shfl_xor(mx, m));
    float e = __expf(sc - mx);
    float se = e;
#pragma unroll
    for (int m = 1; m < 16; m <<= 1) se += __shfl_xor(se, m);
    float wv = wts[b * 16 + kn];
    float num = (e / se) * wv;
    float den = num;
#pragma unroll
    for (int m = 1; m < 16; m <<= 1) den += __shfl_xor(den, m);
    float attn = num / (den + 1e-8f);
    if (half == 0) at[w][h * 16 + kn] = attn;
    __syncthreads();

    // ctx: lane -> (h2, 8 dims)
    const int h2 = lane >> 5;
    const int db = (lane & 31) * 8;
    float acc[8];
#pragma unroll
    for (int i = 0; i < 8; ++i) acc[i] = 0.f;
#pragma unroll
    for (int kk = 0; kk < 16; ++kk) {
        float a = at[w][h2 * 16 + kk];
        uint4 xv = *reinterpret_cast<const uint4*>(&xs[w][kk * XSS + db]);
        const ushort_t* xu = reinterpret_cast<const ushort_t*>(&xv);
#pragma unroll
        for (int i = 0; i < 8; ++i) acc[i] += a * bf2f(xu[i]);
    }
    ushort_t o[8];
#pragma unroll
    for (int i = 0; i < 8; ++i) o[i] = f2bf(acc[i]);
    *reinterpret_cast<uint4*>(&ctx[b * 512 + h2 * 256 + db]) = *reinterpret_cast<uint4*>(o);
}

// ---------------------------------------------------------------------------
// K3: out[b][n] = valid[b] ? (sum_i ctx[b][i]*WoutB[n][i] + bias[n])
//                          : center[b][n]
// same tiling as K1, K=512, N=256
// ---------------------------------------------------------------------------
__global__ __launch_bounds__(256) void gemm_out(
        const ushort_t* __restrict__ Abf, const ushort_t* __restrict__ Bw,
        const float* __restrict__ bias, const int* __restrict__ mask,
        const float* __restrict__ center, float* __restrict__ Out) {
    __shared__ ushort_t As[64 * LDT];
    __shared__ ushort_t Bs[128 * LDT];
    const int t = threadIdx.x;
    const int m0 = blockIdx.x * 64;
    const int n0 = blockIdx.y * 128;
    const int lane = t & 63;
    const int w = t >> 6;
    const int wm = (w & 1) * 32;
    const int wn = (w >> 1) * 64;

    f32x4 zero = {0.f, 0.f, 0.f, 0.f};
    f32x4 acc[2][4];
#pragma unroll
    for (int i = 0; i < 2; ++i)
#pragma unroll
        for (int j = 0; j < 4; ++j) acc[i][j] = zero;

    for (int kc = 0; kc < 512; kc += 64) {
        __syncthreads();
        // stage A (bf16): 64x64
#pragma unroll
        for (int i = 0; i < 2; ++i) {
            int f = i * 2048 + t * 8;
            int r = f >> 6;
            int c = f & 63;
            uint4 v = *reinterpret_cast<const uint4*>(&Abf[(size_t)(m0 + r) * 512 + kc + c]);
            *reinterpret_cast<uint4*>(&As[r * LDT + c]) = v;
        }
        // stage B (bf16): 128x64
#pragma unroll
        for (int i = 0; i < 4; ++i) {
            int f = i * 2048 + t * 8;
            int r = f >> 6;
            int c = f & 63;
            uint4 v = *reinterpret_cast<const uint4*>(&Bw[(size_t)(n0 + r) * 512 + kc + c]);
            *reinterpret_cast<uint4*>(&Bs[r * LDT + c]) = v;
        }
        __syncthreads();
#pragma unroll
        for (int s = 0; s < 2; ++s) {
            int kb = s * 32 + (lane >> 4) * 8;
            bf16x8 af[2], bfr[4];
#pragma unroll
            for (int i = 0; i < 2; ++i)
                af[i] = *reinterpret_cast<const bf16x8*>(&As[(wm + i * 16 + (lane & 15)) * LDT + kb]);
#pragma unroll
            for (int j = 0; j < 4; ++j)
                bfr[j] = *reinterpret_cast<const bf16x8*>(&Bs[(wn + j * 16 + (lane & 15)) * LDT + kb]);
#pragma unroll
            for (int i = 0; i < 2; ++i)
#pragma unroll
                for (int j = 0; j < 4; ++j)
                    acc[i][j] = __builtin_amdgcn_mfma_f32_16x16x32_bf16(af[i], bfr[j], acc[i][j], 0, 0, 0);
        }
    }
    const int cn = lane & 15;
    const int r4 = (lane >> 4) * 4;
#pragma unroll
    for (int i = 0; i < 2; ++i)
#pragma unroll
        for (int j = 0; j < 4; ++j)
#pragma unroll
            for (int r = 0; r < 4; ++r) {
                int m = m0 + wm + i * 16 + r4 + r;
                int n = n0 + wn + j * 16 + cn;
                float val = acc[i][j][r] + bias[n];
                float res = (mask[m] != 0) ? val : center[(size_t)m * 256 + n];
                Out[(size_t)m * 256 + n] = res;
            }
}

// ---------------------------------------------------------------------------
extern "C" void kernel_launch(void* const* d_in, const int* in_sizes, int n_in,
                              void* d_out, int out_size, void* d_ws, size_t ws_size,
                              hipStream_t stream) {
    const float* center = (const float*)d_in[0];
    const float* neigh  = (const float*)d_in[1];
    const float* wts    = (const float*)d_in[2];
    const int*   mask   = (const int*)d_in[3];
    const float* Wq     = (const float*)d_in[4];
    const float* Wk     = (const float*)d_in[5];
    const float* Wout   = (const float*)d_in[6];
    const float* bias   = (const float*)d_in[7];
    float* out = (float*)d_out;

    char* ws = (char*)d_ws;
    ushort_t* Mcomb  = (ushort_t*)(ws);                        // 512*256*2   = 256 KB
    ushort_t* WoutB  = (ushort_t*)(ws + (1 << 18));            // 256 KB
    ushort_t* qkbuf  = (ushort_t*)(ws + (1 << 19));            // 32768*512*2 = 32 MB
    ushort_t* ctxbuf = (ushort_t*)(ws + (1 << 19) + (32u << 20));

    prep_kernel<<<512, 256, 0, stream>>>(Wq, Wk, Wout, Mcomb, WoutB);
    gemm_qk<<<dim3(512, 4), 256, 0, stream>>>(center, Mcomb, qkbuf);
    attn_kernel<<<8192, 256, 0, stream>>>(neigh, wts, qkbuf, ctxbuf);
    gemm_out<<<dim3(512, 2), 256, 0, stream>>>(ctxbuf, WoutB, bias, mask, center, out);
}

// Round 2
// 754.072 us; speedup vs baseline: 1.0497x; 1.0497x over previous
//
#include <hip/hip_runtime.h>
#include <hip/hip_bf16.h>

typedef unsigned short ushort_t;
typedef unsigned int uint32;

typedef __attribute__((ext_vector_type(8))) short bf16x8;
typedef __attribute__((ext_vector_type(4))) float f32x4;

__device__ __forceinline__ ushort_t f2bf(float f) {
    uint32 u = __float_as_uint(f);
    u += 0x7FFFu + ((u >> 16) & 1u);   // round-to-nearest-even
    return (ushort_t)(u >> 16);
}
__device__ __forceinline__ float bf2f(ushort_t b) {
    return __uint_as_float(((uint32)b) << 16);
}

// ---------------------------------------------------------------------------
// K0: Mcomb[h*256+d][e] = sum_a W_k[h][a][d] * W_q[h][a][e] / 8   (bf16)
//     WoutB = bf16(W_out)
// ---------------------------------------------------------------------------
__global__ __launch_bounds__(256) void prep_kernel(
        const float* __restrict__ Wq, const float* __restrict__ Wk,
        const float* __restrict__ Wout,
        ushort_t* __restrict__ Mcomb, ushort_t* __restrict__ WoutB) {
    int idx = blockIdx.x * 256 + threadIdx.x;   // 0..131071
    int n = idx >> 8;        // 0..511
    int e = idx & 255;
    int h = n >> 8;
    int d = n & 255;
    const float* wk = Wk + (h << 14);
    const float* wq = Wq + (h << 14);
    float acc = 0.f;
#pragma unroll 8
    for (int a = 0; a < 64; ++a) {
        acc += wk[(a << 8) + d] * wq[(a << 8) + e];
    }
    Mcomb[idx] = f2bf(acc * 0.125f);
    WoutB[idx] = f2bf(Wout[idx]);
}

// ---------------------------------------------------------------------------
// K1: qk[b][n] = sum_e center[b][e] * Mcomb[n][e]    (bf16 out)
// tile: BM=64, BN=128, BK=64; 4 waves (2x2), wave = 32x64 (2x4 MFMA)
// epilogue: LDS repack (reuse Bs) -> uint4 coalesced stores
// ---------------------------------------------------------------------------
#define LDT 72    // padded LDS row stride (ushorts)
#define CST 136   // epilogue repack stride (ushorts)

__global__ __launch_bounds__(256) void gemm_qk(
        const float* __restrict__ A, const ushort_t* __restrict__ Bw,
        ushort_t* __restrict__ C) {
    __shared__ ushort_t As[64 * LDT];    // 9216 B
    __shared__ ushort_t Bs[128 * LDT];   // 18432 B
    const int t = threadIdx.x;
    const int m0 = blockIdx.x * 64;
    const int n0 = blockIdx.y * 128;
    const int lane = t & 63;
    const int w = t >> 6;
    const int wm = (w & 1) * 32;
    const int wn = (w >> 1) * 64;

    f32x4 zero = {0.f, 0.f, 0.f, 0.f};
    f32x4 acc[2][4];
#pragma unroll
    for (int i = 0; i < 2; ++i)
#pragma unroll
        for (int j = 0; j < 4; ++j) acc[i][j] = zero;

    for (int kc = 0; kc < 256; kc += 64) {
        __syncthreads();
        // stage A (fp32 -> bf16): 64x64
#pragma unroll
        for (int i = 0; i < 4; ++i) {
            int f = i * 1024 + t * 4;
            int r = f >> 6;
            int c = f & 63;
            float4 v = *reinterpret_cast<const float4*>(&A[(size_t)(m0 + r) * 256 + kc + c]);
            ushort_t p[4] = {f2bf(v.x), f2bf(v.y), f2bf(v.z), f2bf(v.w)};
            *reinterpret_cast<uint2*>(&As[r * LDT + c]) = *reinterpret_cast<uint2*>(p);
        }
        // stage B (bf16): 128x64
#pragma unroll
        for (int i = 0; i < 4; ++i) {
            int f = i * 2048 + t * 8;
            int r = f >> 6;
            int c = f & 63;
            uint4 v = *reinterpret_cast<const uint4*>(&Bw[(size_t)(n0 + r) * 256 + kc + c]);
            *reinterpret_cast<uint4*>(&Bs[r * LDT + c]) = v;
        }
        __syncthreads();
#pragma unroll
        for (int s = 0; s < 2; ++s) {
            int kb = s * 32 + (lane >> 4) * 8;
            bf16x8 af[2], bfr[4];
#pragma unroll
            for (int i = 0; i < 2; ++i)
                af[i] = *reinterpret_cast<const bf16x8*>(&As[(wm + i * 16 + (lane & 15)) * LDT + kb]);
#pragma unroll
            for (int j = 0; j < 4; ++j)
                bfr[j] = *reinterpret_cast<const bf16x8*>(&Bs[(wn + j * 16 + (lane & 15)) * LDT + kb]);
#pragma unroll
            for (int i = 0; i < 2; ++i)
#pragma unroll
                for (int j = 0; j < 4; ++j)
                    acc[i][j] = __builtin_amdgcn_mfma_f32_16x16x32_bf16(af[i], bfr[j], acc[i][j], 0, 0, 0);
        }
    }
    // epilogue: repack through Bs (64x128 bf16 tile, stride CST)
    __syncthreads();
    const int cn = lane & 15;
    const int r4 = (lane >> 4) * 4;
#pragma unroll
    for (int i = 0; i < 2; ++i)
#pragma unroll
        for (int j = 0; j < 4; ++j)
#pragma unroll
            for (int r = 0; r < 4; ++r) {
                int row = wm + i * 16 + r4 + r;
                int col = wn + j * 16 + cn;
                Bs[row * CST + col] = f2bf(acc[i][j][r]);
            }
    __syncthreads();
#pragma unroll
    for (int it = 0; it < 4; ++it) {
        int row = it * 16 + (t >> 4);
        int cb = (t & 15) * 8;
        uint4 v = *reinterpret_cast<const uint4*>(&Bs[row * CST + cb]);
        *reinterpret_cast<uint4*>(&C[(size_t)(m0 + row) * 512 + n0 + cb]) = v;
    }
}

// ---------------------------------------------------------------------------
// K2: per valid row b: scores -> softmax*w renorm -> ctx. Invalid rows skipped
// (output for them is center, handled in K3). 1 wave/row, 4 rows/block.
// ---------------------------------------------------------------------------
#define XSS 264   // xs row stride in ushorts

__global__ __launch_bounds__(256) void attn_kernel(
        const float* __restrict__ neigh, const float* __restrict__ wts,
        const ushort_t* __restrict__ qk, const int* __restrict__ mask,
        ushort_t* __restrict__ ctx) {
    __shared__ ushort_t xs[4][16 * XSS];   // 33792 B
    __shared__ float qs[4][512];           // 8192 B
    __shared__ float at[4][32];            // 512 B
    const int t = threadIdx.x;
    const int w = t >> 6;
    const int lane = t & 63;
    const size_t b = (size_t)blockIdx.x * 4 + w;
    const bool active = (mask[b] != 0);    // wave-uniform

    if (active) {
        // stage x: 16 x 256 fp32 -> bf16
        const float* xg = neigh + b * 4096;
#pragma unroll
        for (int k = 0; k < 16; ++k) {
            float4 v = *reinterpret_cast<const float4*>(&xg[k * 256 + lane * 4]);
            ushort_t p[4] = {f2bf(v.x), f2bf(v.y), f2bf(v.z), f2bf(v.w)};
            *reinterpret_cast<uint2*>(&xs[w][k * XSS + lane * 4]) = *reinterpret_cast<uint2*>(p);
        }
        // stage qk: 512 bf16 -> fp32
        uint4 v = *reinterpret_cast<const uint4*>(&qk[b * 512 + lane * 8]);
        const ushort_t* xu = reinterpret_cast<const ushort_t*>(&v);
        float4 q0 = {bf2f(xu[0]), bf2f(xu[1]), bf2f(xu[2]), bf2f(xu[3])};
        float4 q1 = {bf2f(xu[4]), bf2f(xu[5]), bf2f(xu[6]), bf2f(xu[7])};
        *reinterpret_cast<float4*>(&qs[w][lane * 8]) = q0;
        *reinterpret_cast<float4*>(&qs[w][lane * 8 + 4]) = q1;
    }
    __syncthreads();

    if (active) {
        // scores: lane -> (h,k,half); 2 lanes per (h,k) dot of 256
        const int p = lane & 31;
        const int half = lane >> 5;
        const int h = p >> 4;
        const int kn = p & 15;
        const ushort_t* xrow = &xs[w][kn * XSS + half * 128];
        const float* qrow = &qs[w][h * 256 + half * 128];
        float sc = 0.f;
#pragma unroll
        for (int j = 0; j < 16; ++j) {
            uint4 xv = *reinterpret_cast<const uint4*>(xrow + j * 8);
            const ushort_t* xu = reinterpret_cast<const ushort_t*>(&xv);
            float4 q0 = *reinterpret_cast<const float4*>(qrow + j * 8);
            float4 q1 = *reinterpret_cast<const float4*>(qrow + j * 8 + 4);
            sc += bf2f(xu[0]) * q0.x;
            sc += bf2f(xu[1]) * q0.y;
            sc += bf2f(xu[2]) * q0.z;
            sc += bf2f(xu[3]) * q0.w;
            sc += bf2f(xu[4]) * q1.x;
            sc += bf2f(xu[5]) * q1.y;
            sc += bf2f(xu[6]) * q1.z;
            sc += bf2f(xu[7]) * q1.w;
        }
        sc += __shfl_xor(sc, 32);

        float mx = sc;
#pragma unroll
        for (int m = 1; m < 16; m <<= 1) mx = fmaxf(mx, __shfl_xor(mx, m));
        float e = __expf(sc - mx);
        float se = e;
#pragma unroll
        for (int m = 1; m < 16; m <<= 1) se += __shfl_xor(se, m);
        float wv = wts[b * 16 + kn];
        float num = (e / se) * wv;
        float den = num;
#pragma unroll
        for (int m = 1; m < 16; m <<= 1) den += __shfl_xor(den, m);
        float attn = num / (den + 1e-8f);
        if (half == 0) at[w][h * 16 + kn] = attn;
    }
    __syncthreads();

    if (active) {
        const int h2 = lane >> 5;
        const int db = (lane & 31) * 8;
        float acc[8];
#pragma unroll
        for (int i = 0; i < 8; ++i) acc[i] = 0.f;
#pragma unroll
        for (int kk = 0; kk < 16; ++kk) {
            float a = at[w][h2 * 16 + kk];
            uint4 xv = *reinterpret_cast<const uint4*>(&xs[w][kk * XSS + db]);
            const ushort_t* xu = reinterpret_cast<const ushort_t*>(&xv);
#pragma unroll
            for (int i = 0; i < 8; ++i) acc[i] += a * bf2f(xu[i]);
        }
        ushort_t o[8];
#pragma unroll
        for (int i = 0; i < 8; ++i) o[i] = f2bf(acc[i]);
        *reinterpret_cast<uint4*>(&ctx[b * 512 + h2 * 256 + db]) = *reinterpret_cast<uint4*>(o);
    }
}

// ---------------------------------------------------------------------------
// K3: out[b][n] = valid[b] ? (ctx[b] . WoutB[n] + bias[n]) : center[b][n]
// tile: BM=64, BN=256 (full N, ctx read once), BK=64; wave tile 32x128
// ---------------------------------------------------------------------------
__global__ __launch_bounds__(256) void gemm_out(
        const ushort_t* __restrict__ Abf, const ushort_t* __restrict__ Bw,
        const float* __restrict__ bias, const int* __restrict__ mask,
        const float* __restrict__ center, float* __restrict__ Out) {
    __shared__ ushort_t As[64 * LDT];     // 9216 B
    __shared__ ushort_t Bs[256 * LDT];    // 36864 B
    const int t = threadIdx.x;
    const int m0 = blockIdx.x * 64;
    const int lane = t & 63;
    const int w = t >> 6;
    const int wm = (w & 1) * 32;
    const int wn = (w >> 1) * 128;

    f32x4 zero = {0.f, 0.f, 0.f, 0.f};
    f32x4 acc[2][8];
#pragma unroll
    for (int i = 0; i < 2; ++i)
#pragma unroll
        for (int j = 0; j < 8; ++j) acc[i][j] = zero;

    for (int kc = 0; kc < 512; kc += 64) {
        __syncthreads();
        // stage A (bf16): 64x64
#pragma unroll
        for (int i = 0; i < 2; ++i) {
            int f = i * 2048 + t * 8;
            int r = f >> 6;
            int c = f & 63;
            uint4 v = *reinterpret_cast<const uint4*>(&Abf[(size_t)(m0 + r) * 512 + kc + c]);
            *reinterpret_cast<uint4*>(&As[r * LDT + c]) = v;
        }
        // stage B (bf16): 256x64
#pragma unroll
        for (int i = 0; i < 8; ++i) {
            int f = i * 2048 + t * 8;
            int r = f >> 6;
            int c = f & 63;
            uint4 v = *reinterpret_cast<const uint4*>(&Bw[(size_t)r * 512 + kc + c]);
            *reinterpret_cast<uint4*>(&Bs[r * LDT + c]) = v;
        }
        __syncthreads();
#pragma unroll
        for (int s = 0; s < 2; ++s) {
            int kb = s * 32 + (lane >> 4) * 8;
            bf16x8 af[2], bfr[8];
#pragma unroll
            for (int i = 0; i < 2; ++i)
                af[i] = *reinterpret_cast<const bf16x8*>(&As[(wm + i * 16 + (lane & 15)) * LDT + kb]);
#pragma unroll
            for (int j = 0; j < 8; ++j)
                bfr[j] = *reinterpret_cast<const bf16x8*>(&Bs[(wn + j * 16 + (lane & 15)) * LDT + kb]);
#pragma unroll
            for (int i = 0; i < 2; ++i)
#pragma unroll
                for (int j = 0; j < 8; ++j)
                    acc[i][j] = __builtin_amdgcn_mfma_f32_16x16x32_bf16(af[i], bfr[j], acc[i][j], 0, 0, 0);
        }
    }
    const int cn = lane & 15;
    const int r4 = (lane >> 4) * 4;
    int mk[2][4];
#pragma unroll
    for (int i = 0; i < 2; ++i)
#pragma unroll
        for (int r = 0; r < 4; ++r) mk[i][r] = mask[m0 + wm + i * 16 + r4 + r];
#pragma unroll
    for (int i = 0; i < 2; ++i)
#pragma unroll
        for (int j = 0; j < 8; ++j)
#pragma unroll
            for (int r = 0; r < 4; ++r) {
                int m = m0 + wm + i * 16 + r4 + r;
                int n = wn + j * 16 + cn;
                float res;
                if (mk[i][r]) res = acc[i][j][r] + bias[n];
                else          res = center[(size_t)m * 256 + n];
                Out[(size_t)m * 256 + n] = res;
            }
}

// ---------------------------------------------------------------------------
extern "C" void kernel_launch(void* const* d_in, const int* in_sizes, int n_in,
                              void* d_out, int out_size, void* d_ws, size_t ws_size,
                              hipStream_t stream) {
    const float* center = (const float*)d_in[0];
    const float* neigh  = (const float*)d_in[1];
    const float* wts    = (const float*)d_in[2];
    const int*   mask   = (const int*)d_in[3];
    const float* Wq     = (const float*)d_in[4];
    const float* Wk     = (const float*)d_in[5];
    const float* Wout   = (const float*)d_in[6];
    const float* bias   = (const float*)d_in[7];
    float* out = (float*)d_out;

    char* ws = (char*)d_ws;
    ushort_t* Mcomb  = (ushort_t*)(ws);                        // 256 KB
    ushort_t* WoutB  = (ushort_t*)(ws + (1 << 18));            // 256 KB
    ushort_t* qkbuf  = (ushort_t*)(ws + (1 << 19));            // 32 MB
    ushort_t* ctxbuf = (ushort_t*)(ws + (1 << 19) + (32u << 20));

    prep_kernel<<<512, 256, 0, stream>>>(Wq, Wk, Wout, Mcomb, WoutB);
    gemm_qk<<<dim3(512, 4), 256, 0, stream>>>(center, Mcomb, qkbuf);
    attn_kernel<<<8192, 256, 0, stream>>>(neigh, wts, qkbuf, mask, ctxbuf);
    gemm_out<<<512, 256, 0, stream>>>(ctxbuf, WoutB, bias, mask, center, out);
}